// Round 5
// baseline (1063.352 us; speedup 1.0000x reference)
//
#include <hip/hip_runtime.h>
#include <hip/hip_bf16.h>

typedef __bf16 bf16_t;
typedef bf16_t bf16x8 __attribute__((ext_vector_type(8)));
typedef float  f32x4  __attribute__((ext_vector_type(4)));

#define S_LEN  2048
#define DMODEL 2048
#define NH     16
#define DH     128
#define BATCH  2
#define MROWS  (BATCH * S_LEN)   // 4096

#define NEG_BIG (-1.0e30f)

#define BAR()   asm volatile("s_barrier" ::: "memory")
#define LGKM0() asm volatile("s_waitcnt lgkmcnt(0)" ::: "memory")

__device__ __forceinline__ bf16x8 cvt8_f32_bf16(const float* __restrict__ p) {
  float4 f0 = *(const float4*)(p);
  float4 f1 = *(const float4*)(p + 4);
  bf16x8 r;
  r[0] = (bf16_t)f0.x; r[1] = (bf16_t)f0.y; r[2] = (bf16_t)f0.z; r[3] = (bf16_t)f0.w;
  r[4] = (bf16_t)f1.x; r[5] = (bf16_t)f1.y; r[6] = (bf16_t)f1.z; r[7] = (bf16_t)f1.w;
  return r;
}

// async global(16B/lane) -> LDS. Dest = wave-uniform base + lane*16 (m97/m104).
__device__ __forceinline__ void gld16(const void* g, void* l) {
  __builtin_amdgcn_global_load_lds(
      (const __attribute__((address_space(1))) void*)g,
      (__attribute__((address_space(3))) void*)l, 16, 0, 0);
}

// ---------------- fp32 -> bf16 conversion ----------------
__global__ __launch_bounds__(256)
void cvt_bf16(const float* __restrict__ s, bf16_t* __restrict__ d, int n8) {
  int i = blockIdx.x * 256 + threadIdx.x;
  if (i < n8) *(bf16x8*)(&d[(size_t)i * 8]) = cvt8_f32_bf16(&s[(size_t)i * 8]);
}

// ---------------- GEMM: C = (A @ W^T + bias) * oscale ----------------
// m97 structure: BK=32, unpadded LDS, global_load_lds for bf16 operands.
// mode 0: C[row*N+col]; 1: [B,H,S,DH]; 2: [B,H,DH,S] (V transposed)
template <typename TA, typename TW, typename TC>
__global__ __launch_bounds__(256)
void gemm_bt(const TA* __restrict__ A, const TW* __restrict__ W,
             const float* __restrict__ bias, TC* __restrict__ C,
             int mode, float oscale)
{
  constexpr int K = DMODEL, N = DMODEL;
  __shared__ __align__(16) bf16_t As[128 * 32];
  __shared__ __align__(16) bf16_t Bs[128 * 32];
  const int tid  = threadIdx.x;
  const int wave = tid >> 6, lane = tid & 63;
  const int quad = lane >> 4, l16 = lane & 15;
  const int bm = blockIdx.x * 128, bn = blockIdx.y * 128;
  const int wm = (wave >> 1) * 64, wn = (wave & 1) * 64;

  f32x4 acc[4][4] = {};

  for (int k0 = 0; k0 < K; k0 += 32) {
    __syncthreads();
    if constexpr (__is_same(TA, float)) {
#pragma unroll
      for (int i = 0; i < 2; ++i) {
        int c = tid + i * 256, row = c >> 2, col = (c & 3) << 3;
        *(bf16x8*)(&As[row * 32 + col]) =
            cvt8_f32_bf16(&A[(size_t)(bm + row) * K + k0 + col]);
      }
    } else {
#pragma unroll
      for (int t = 0; t < 2; ++t) {
        int chunk = wave * 128 + t * 64 + lane;
        int row = chunk >> 2, col = (chunk & 3) << 3;
        gld16(&A[(size_t)(bm + row) * K + k0 + col], &As[row * 32 + col]);
      }
    }
    if constexpr (__is_same(TW, float)) {
#pragma unroll
      for (int i = 0; i < 2; ++i) {
        int c = tid + i * 256, row = c >> 2, col = (c & 3) << 3;
        *(bf16x8*)(&Bs[row * 32 + col]) =
            cvt8_f32_bf16(&W[(size_t)(bn + row) * K + k0 + col]);
      }
    } else {
#pragma unroll
      for (int t = 0; t < 2; ++t) {
        int chunk = wave * 128 + t * 64 + lane;
        int row = chunk >> 2, col = (chunk & 3) << 3;
        gld16(&W[(size_t)(bn + row) * K + k0 + col], &Bs[row * 32 + col]);
      }
    }
    __syncthreads();
    bf16x8 af[4], bfr[4];
#pragma unroll
    for (int i = 0; i < 4; ++i) {
      af[i]  = *(const bf16x8*)(&As[(wm + i * 16 + l16) * 32 + quad * 8]);
      bfr[i] = *(const bf16x8*)(&Bs[(wn + i * 16 + l16) * 32 + quad * 8]);
    }
#pragma unroll
    for (int mi = 0; mi < 4; ++mi)
#pragma unroll
      for (int ni = 0; ni < 4; ++ni)
        acc[mi][ni] = __builtin_amdgcn_mfma_f32_16x16x32_bf16(
            af[mi], bfr[ni], acc[mi][ni], 0, 0, 0);
  }

#pragma unroll
  for (int mi = 0; mi < 4; ++mi) {
#pragma unroll
    for (int ni = 0; ni < 4; ++ni) {
      int col = bn + wn + ni * 16 + l16;
      float bval = bias[col];
#pragma unroll
      for (int r = 0; r < 4; ++r) {
        int row = bm + wm + mi * 16 + quad * 4 + r;
        float vv = (acc[mi][ni][r] + bval) * oscale;
        size_t idx;
        if (mode == 0) {
          idx = (size_t)row * N + col;
        } else {
          int b = row >> 11, s = row & (S_LEN - 1);
          int h = col >> 7,  d = col & (DH - 1);
          if (mode == 1) idx = (((size_t)(b * NH + h)) * S_LEN + s) * DH + d;
          else           idx = (((size_t)(b * NH + h)) * DH + d) * S_LEN + s;
        }
        C[idx] = (TC)vv;
      }
    }
  }
}

// ---------------- Flash attention, paired Q-tiles for exact balance ----------
// Q (pre-scaled): [B*NH,S,DH]  K: [B*NH,S,DH]  V: [B*NH,DH,S]  O: [B,S,D]
// Block = (bh, pair): handles 64-row Q-tiles p and 31-p. Work = 33 tile-units
// for every block under causal. Raw s_barrier keeps prefetch loads in flight.
__device__ __forceinline__ void softmax_tile(
    f32x4* sc, float* mrow, float* lrow, f32x4* oacc,
    int rowbase, int kb, bool do_mask, int quad, int l16, bf16_t* Pw)
{
  float p[4][4];
#pragma unroll
  for (int nf = 0; nf < 4; ++nf)
#pragma unroll
    for (int r = 0; r < 4; ++r) {
      float s = sc[nf][r];
      if (do_mask && (kb * 64 + nf * 16 + l16 > rowbase + quad * 4 + r)) s = NEG_BIG;
      p[nf][r] = s;
    }
#pragma unroll
  for (int r = 0; r < 4; ++r) {
    float mx = fmaxf(fmaxf(p[0][r], p[1][r]), fmaxf(p[2][r], p[3][r]));
#pragma unroll
    for (int d = 8; d >= 1; d >>= 1) mx = fmaxf(mx, __shfl_xor(mx, d));
    float mnew  = fmaxf(mrow[r], mx);
    float alpha = __expf(mrow[r] - mnew);
    mrow[r] = mnew;
    float rsum = 0.f;
#pragma unroll
    for (int nf = 0; nf < 4; ++nf) {
      float e = __expf(p[nf][r] - mnew);
      p[nf][r] = e;
      rsum += e;
    }
#pragma unroll
    for (int d = 8; d >= 1; d >>= 1) rsum += __shfl_xor(rsum, d);
    lrow[r] = lrow[r] * alpha + rsum;
#pragma unroll
    for (int nf = 0; nf < 8; ++nf) oacc[nf][r] *= alpha;
  }
#pragma unroll
  for (int r = 0; r < 4; ++r)
#pragma unroll
    for (int nf = 0; nf < 4; ++nf)
      Pw[(quad * 4 + r) * 72 + nf * 16 + l16] = (bf16_t)p[nf][r];
}

__global__ __launch_bounds__(256, 2)
void attn_fwd(const bf16_t* __restrict__ Q, const bf16_t* __restrict__ Kh,
              const bf16_t* __restrict__ Vt, bf16_t* __restrict__ O,
              const int* __restrict__ causal_p)
{
  __shared__ __align__(16) bf16_t Ks[64 * 136];
  __shared__ __align__(16) bf16_t Vs[128 * 72];
  __shared__ __align__(16) bf16_t Ps[4][2][16 * 72];
  const int tid  = threadIdx.x;
  const int wave = tid >> 6, lane = tid & 63;
  const int quad = lane >> 4, l16 = lane & 15;
  const int id = blockIdx.x;
  const int bh = id & 31, pair = id >> 5;   // bh-major: one bh's blocks share an XCD
  const int causal = *causal_p;
  const int tlo = pair, thi = 31 - pair;    // 64-row Q-tile indices
  const int nkb = causal ? (thi + 1) : 32;

  const bf16_t* Qb = Q  + (size_t)bh * S_LEN * DH;
  const bf16_t* Kb = Kh + (size_t)bh * S_LEN * DH;
  const bf16_t* Vb = Vt + (size_t)bh * DH * S_LEN;

  bf16x8 qfl[4], qfh[4];
#pragma unroll
  for (int kk = 0; kk < 4; ++kk) {
    qfl[kk] = *(const bf16x8*)(&Qb[(size_t)(tlo * 64 + wave * 16 + l16) * DH + kk * 32 + quad * 8]);
    qfh[kk] = *(const bf16x8*)(&Qb[(size_t)(thi * 64 + wave * 16 + l16) * DH + kk * 32 + quad * 8]);
  }

  f32x4 ol[8] = {}, oh[8] = {};
  float ml[4], ll[4], mh[4], lh[4];
#pragma unroll
  for (int r = 0; r < 4; ++r) { ml[r] = mh[r] = NEG_BIG; ll[r] = lh[r] = 0.f; }

  float4 ka[4], va[4];
#define LOAD_TILE(kb_)                                                          \
  {                                                                             \
    _Pragma("unroll")                                                           \
    for (int i = 0; i < 4; ++i) {                                               \
      int c = tid + i * 256;                                                    \
      ka[i] = *(const float4*)(&Kb[(size_t)((kb_) * 64 + (c >> 4)) * DH + ((c & 15) << 3)]); \
      va[i] = *(const float4*)(&Vb[(size_t)(c >> 3) * S_LEN + (kb_) * 64 + ((c & 7) << 3)]); \
    }                                                                           \
  }

  LOAD_TILE(0)
  for (int kb = 0; kb < nkb; ++kb) {
    if (kb) BAR();                       // all waves done reading tile kb-1
#pragma unroll
    for (int i = 0; i < 4; ++i) {        // vmcnt waits attach to ka/va use here
      int c = tid + i * 256;
      *(float4*)(&Ks[(c >> 4) * 136 + ((c & 15) << 3)]) = ka[i];
      *(float4*)(&Vs[(c >> 3) * 72 + ((c & 7) << 3)])   = va[i];
    }
    LGKM0(); BAR();                      // publish tile kb (no vmcnt drain!)
    if (kb + 1 < nkb) LOAD_TILE(kb + 1)  // stays in flight through compute

    const bool lo_on = (!causal) || (kb <= tlo);

    // ---- scores: hi always, lo when active ----
    f32x4 scl[4] = {}, sch[4] = {};
#pragma unroll
    for (int kk = 0; kk < 4; ++kk) {
      bf16x8 kf[4];
#pragma unroll
      for (int nf = 0; nf < 4; ++nf)
        kf[nf] = *(const bf16x8*)(&Ks[(nf * 16 + l16) * 136 + kk * 32 + quad * 8]);
#pragma unroll
      for (int nf = 0; nf < 4; ++nf) {
        sch[nf] = __builtin_amdgcn_mfma_f32_16x16x32_bf16(qfh[kk], kf[nf], sch[nf], 0, 0, 0);
        if (lo_on)
          scl[nf] = __builtin_amdgcn_mfma_f32_16x16x32_bf16(qfl[kk], kf[nf], scl[nf], 0, 0, 0);
      }
    }

    bf16_t* Ph = &Ps[wave][1][0];
    bf16_t* Pl = &Ps[wave][0][0];
    softmax_tile(sch, mh, lh, oh, thi * 64 + wave * 16, kb,
                 causal && (kb == thi), quad, l16, Ph);
    if (lo_on)
      softmax_tile(scl, ml, ll, ol, tlo * 64 + wave * 16, kb,
                   causal && (kb == tlo), quad, l16, Pl);
    LGKM0();                             // P writes visible (wave-local)

    // ---- O += P V (vf shared across both Q-tiles) ----
#pragma unroll
    for (int ks = 0; ks < 2; ++ks) {
      bf16x8 pfh = *(const bf16x8*)(&Ph[l16 * 72 + ks * 32 + quad * 8]);
      bf16x8 pfl = *(const bf16x8*)(&Pl[l16 * 72 + ks * 32 + quad * 8]);
#pragma unroll
      for (int nf = 0; nf < 8; ++nf) {
        bf16x8 vf = *(const bf16x8*)(&Vs[(nf * 16 + l16) * 72 + ks * 32 + quad * 8]);
        oh[nf] = __builtin_amdgcn_mfma_f32_16x16x32_bf16(pfh, vf, oh[nf], 0, 0, 0);
        if (lo_on)
          ol[nf] = __builtin_amdgcn_mfma_f32_16x16x32_bf16(pfl, vf, ol[nf], 0, 0, 0);
      }
    }
  }

  // epilogue: both Q-tiles
  const int b = bh >> 4, h = bh & 15;
#pragma unroll
  for (int nf = 0; nf < 8; ++nf) {
    int dh = nf * 16 + l16;
#pragma unroll
    for (int r = 0; r < 4; ++r) {
      int sl = tlo * 64 + wave * 16 + quad * 4 + r;
      int sh = thi * 64 + wave * 16 + quad * 4 + r;
      O[((size_t)(b * S_LEN + sl)) * DMODEL + h * DH + dh] =
          (bf16_t)(ol[nf][r] / fmaxf(ll[r], 1e-20f));
      O[((size_t)(b * S_LEN + sh)) * DMODEL + h * DH + dh] =
          (bf16_t)(oh[nf][r] / fmaxf(lh[r], 1e-20f));
    }
  }
}

extern "C" void kernel_launch(void* const* d_in, const int* in_sizes, int n_in,
                              void* d_out, int out_size, void* d_ws, size_t ws_size,
                              hipStream_t stream) {
  const float* q  = (const float*)d_in[0];
  const float* k  = (const float*)d_in[1];
  const float* v  = (const float*)d_in[2];
  const float* Wq = (const float*)d_in[3];
  const float* bq = (const float*)d_in[4];
  const float* Wk = (const float*)d_in[5];
  const float* bk = (const float*)d_in[6];
  const float* Wv = (const float*)d_in[7];
  const float* bv = (const float*)d_in[8];
  const float* Wo = (const float*)d_in[9];
  const float* bo = (const float*)d_in[10];
  const int*   cm = (const int*)d_in[11];

  float* out = (float*)d_out;
  const size_t NA = (size_t)MROWS * DMODEL;     // 8,388,608
  const size_t NW = (size_t)DMODEL * DMODEL;    // 4,194,304
  const float qscale = 0.08838834764831845f;    // 1/sqrt(128)

  bf16_t* p0 = (bf16_t*)d_ws;
  const size_t needA = (4 * NW + 7 * NA) * sizeof(bf16_t);  // ~151 MB
  const size_t needB = (4 * NW + 4 * NA) * sizeof(bf16_t);  // ~101 MB

  dim3 gg(MROWS / 128, DMODEL / 128), bb(256);
  dim3 cgW(2048), cgA(4096);
  bf16_t *Qh, *Kh, *Vh, *Ao;

  if (ws_size >= needA) {
    bf16_t *Wqb = p0, *Wkb = p0 + NW, *Wvb = p0 + 2 * NW, *Wob = p0 + 3 * NW;
    bf16_t *qb2 = p0 + 4 * NW, *kb2 = qb2 + NA, *vb2 = kb2 + NA;
    Qh = vb2 + NA; Kh = Qh + NA; Vh = Kh + NA; Ao = Vh + NA;
    cvt_bf16<<<cgW, bb, 0, stream>>>(Wq, Wqb, (int)(NW / 8));
    cvt_bf16<<<cgW, bb, 0, stream>>>(Wk, Wkb, (int)(NW / 8));
    cvt_bf16<<<cgW, bb, 0, stream>>>(Wv, Wvb, (int)(NW / 8));
    cvt_bf16<<<cgW, bb, 0, stream>>>(Wo, Wob, (int)(NW / 8));
    cvt_bf16<<<cgA, bb, 0, stream>>>(q, qb2, (int)(NA / 8));
    cvt_bf16<<<cgA, bb, 0, stream>>>(k, kb2, (int)(NA / 8));
    cvt_bf16<<<cgA, bb, 0, stream>>>(v, vb2, (int)(NA / 8));
    gemm_bt<bf16_t, bf16_t, bf16_t><<<gg, bb, 0, stream>>>(qb2, Wqb, bq, Qh, 1, qscale);
    gemm_bt<bf16_t, bf16_t, bf16_t><<<gg, bb, 0, stream>>>(kb2, Wkb, bk, Kh, 1, 1.0f);
    gemm_bt<bf16_t, bf16_t, bf16_t><<<gg, bb, 0, stream>>>(vb2, Wvb, bv, Vh, 2, 1.0f);
    attn_fwd<<<dim3(512), bb, 0, stream>>>(Qh, Kh, Vh, Ao, cm);
    gemm_bt<bf16_t, bf16_t, float><<<gg, bb, 0, stream>>>(Ao, Wob, bo, out, 0, 1.0f);
  } else if (ws_size >= needB) {
    bf16_t *Wqb = p0, *Wkb = p0 + NW, *Wvb = p0 + 2 * NW, *Wob = p0 + 3 * NW;
    Qh = p0 + 4 * NW; Kh = Qh + NA; Vh = Kh + NA; Ao = Vh + NA;
    cvt_bf16<<<cgW, bb, 0, stream>>>(Wq, Wqb, (int)(NW / 8));
    cvt_bf16<<<cgW, bb, 0, stream>>>(Wk, Wkb, (int)(NW / 8));
    cvt_bf16<<<cgW, bb, 0, stream>>>(Wv, Wvb, (int)(NW / 8));
    cvt_bf16<<<cgW, bb, 0, stream>>>(Wo, Wob, (int)(NW / 8));
    gemm_bt<float, bf16_t, bf16_t><<<gg, bb, 0, stream>>>(q, Wqb, bq, Qh, 1, qscale);
    gemm_bt<float, bf16_t, bf16_t><<<gg, bb, 0, stream>>>(k, Wkb, bk, Kh, 1, 1.0f);
    gemm_bt<float, bf16_t, bf16_t><<<gg, bb, 0, stream>>>(v, Wvb, bv, Vh, 2, 1.0f);
    attn_fwd<<<dim3(512), bb, 0, stream>>>(Qh, Kh, Vh, Ao, cm);
    gemm_bt<bf16_t, bf16_t, float><<<gg, bb, 0, stream>>>(Ao, Wob, bo, out, 0, 1.0f);
  } else {
    Qh = p0; Kh = Qh + NA; Vh = Kh + NA; Ao = Vh + NA;
    gemm_bt<float, float, bf16_t><<<gg, bb, 0, stream>>>(q, Wq, bq, Qh, 1, qscale);
    gemm_bt<float, float, bf16_t><<<gg, bb, 0, stream>>>(k, Wk, bk, Kh, 1, 1.0f);
    gemm_bt<float, float, bf16_t><<<gg, bb, 0, stream>>>(v, Wv, bv, Vh, 2, 1.0f);
    attn_fwd<<<dim3(512), bb, 0, stream>>>(Qh, Kh, Vh, Ao, cm);
    gemm_bt<bf16_t, float, float><<<gg, bb, 0, stream>>>(Ao, Wo, bo, out, 0, 1.0f);
  }
}

// Round 6
// 584.623 us; speedup vs baseline: 1.8189x; 1.8189x over previous
//
#include <hip/hip_runtime.h>
#include <hip/hip_bf16.h>

typedef __bf16 bf16_t;
typedef bf16_t bf16x8 __attribute__((ext_vector_type(8)));
typedef float  f32x4  __attribute__((ext_vector_type(4)));

#define S_LEN  2048
#define DMODEL 2048
#define NH     16
#define DH     128
#define BATCH  2
#define MROWS  (BATCH * S_LEN)   // 4096

#define NEG_BIG (-1.0e30f)

__device__ __forceinline__ bf16x8 cvt8_f32_bf16(const float* __restrict__ p) {
  float4 f0 = *(const float4*)(p);
  float4 f1 = *(const float4*)(p + 4);
  bf16x8 r;
  r[0] = (bf16_t)f0.x; r[1] = (bf16_t)f0.y; r[2] = (bf16_t)f0.z; r[3] = (bf16_t)f0.w;
  r[4] = (bf16_t)f1.x; r[5] = (bf16_t)f1.y; r[6] = (bf16_t)f1.z; r[7] = (bf16_t)f1.w;
  return r;
}

// async global(16B/lane) -> LDS. Dest = wave-uniform base + lane*16 (m97/m104).
__device__ __forceinline__ void gld16(const void* g, void* l) {
  __builtin_amdgcn_global_load_lds(
      (const __attribute__((address_space(1))) void*)g,
      (__attribute__((address_space(3))) void*)l, 16, 0, 0);
}

// ---------------- fp32 -> bf16 conversion ----------------
__global__ __launch_bounds__(256)
void cvt_bf16(const float* __restrict__ s, bf16_t* __restrict__ d, int n8) {
  int i = blockIdx.x * 256 + threadIdx.x;
  if (i < n8) *(bf16x8*)(&d[(size_t)i * 8]) = cvt8_f32_bf16(&s[(size_t)i * 8]);
}

// ---------------- GEMM: C = (A @ W^T + bias) * oscale ----------------
// m97 structure: BK=32, unpadded LDS, global_load_lds for bf16 operands.
// mode 0: C[row*N+col]; 1: [B,H,S,DH]; 2: [B,H,DH,S] (V transposed)
template <typename TA, typename TW, typename TC>
__global__ __launch_bounds__(256)
void gemm_bt(const TA* __restrict__ A, const TW* __restrict__ W,
             const float* __restrict__ bias, TC* __restrict__ C,
             int mode, float oscale)
{
  constexpr int K = DMODEL, N = DMODEL;
  __shared__ __align__(16) bf16_t As[128 * 32];
  __shared__ __align__(16) bf16_t Bs[128 * 32];
  const int tid  = threadIdx.x;
  const int wave = tid >> 6, lane = tid & 63;
  const int quad = lane >> 4, l16 = lane & 15;
  const int bm = blockIdx.x * 128, bn = blockIdx.y * 128;
  const int wm = (wave >> 1) * 64, wn = (wave & 1) * 64;

  f32x4 acc[4][4] = {};

  for (int k0 = 0; k0 < K; k0 += 32) {
    __syncthreads();
    if constexpr (__is_same(TA, float)) {
#pragma unroll
      for (int i = 0; i < 2; ++i) {
        int c = tid + i * 256, row = c >> 2, col = (c & 3) << 3;
        *(bf16x8*)(&As[row * 32 + col]) =
            cvt8_f32_bf16(&A[(size_t)(bm + row) * K + k0 + col]);
      }
    } else {
#pragma unroll
      for (int t = 0; t < 2; ++t) {
        int chunk = wave * 128 + t * 64 + lane;
        int row = chunk >> 2, col = (chunk & 3) << 3;
        gld16(&A[(size_t)(bm + row) * K + k0 + col], &As[row * 32 + col]);
      }
    }
    if constexpr (__is_same(TW, float)) {
#pragma unroll
      for (int i = 0; i < 2; ++i) {
        int c = tid + i * 256, row = c >> 2, col = (c & 3) << 3;
        *(bf16x8*)(&Bs[row * 32 + col]) =
            cvt8_f32_bf16(&W[(size_t)(bn + row) * K + k0 + col]);
      }
    } else {
#pragma unroll
      for (int t = 0; t < 2; ++t) {
        int chunk = wave * 128 + t * 64 + lane;
        int row = chunk >> 2, col = (chunk & 3) << 3;
        gld16(&W[(size_t)(bn + row) * K + k0 + col], &Bs[row * 32 + col]);
      }
    }
    __syncthreads();
    bf16x8 af[4], bfr[4];
#pragma unroll
    for (int i = 0; i < 4; ++i) {
      af[i]  = *(const bf16x8*)(&As[(wm + i * 16 + l16) * 32 + quad * 8]);
      bfr[i] = *(const bf16x8*)(&Bs[(wn + i * 16 + l16) * 32 + quad * 8]);
    }
#pragma unroll
    for (int mi = 0; mi < 4; ++mi)
#pragma unroll
      for (int ni = 0; ni < 4; ++ni)
        acc[mi][ni] = __builtin_amdgcn_mfma_f32_16x16x32_bf16(
            af[mi], bfr[ni], acc[mi][ni], 0, 0, 0);
  }

#pragma unroll
  for (int mi = 0; mi < 4; ++mi) {
#pragma unroll
    for (int ni = 0; ni < 4; ++ni) {
      int col = bn + wn + ni * 16 + l16;
      float bval = bias[col];
#pragma unroll
      for (int r = 0; r < 4; ++r) {
        int row = bm + wm + mi * 16 + quad * 4 + r;
        float vv = (acc[mi][ni][r] + bval) * oscale;
        size_t idx;
        if (mode == 0) {
          idx = (size_t)row * N + col;
        } else {
          int b = row >> 11, s = row & (S_LEN - 1);
          int h = col >> 7,  d = col & (DH - 1);
          if (mode == 1) idx = (((size_t)(b * NH + h)) * S_LEN + s) * DH + d;
          else           idx = (((size_t)(b * NH + h)) * DH + d) * S_LEN + s;
        }
        C[idx] = (TC)vv;
      }
    }
  }
}

// ---------------- Flash attention ----------------
// Q (pre-scaled): [B*NH,S,DH]  K: [B*NH,S,DH]  V: [B*NH,DH,S]  O: [B,S,D]
// 64 Q-rows/block (4 waves x 16), 1024 blocks. Heavy-first dispatch order,
// bh = id&31 pins each head's 32 blocks to one XCD (id%8 == bh%8) for L2 reuse.
// VGPR prefetch: issue tile kb+1 loads AFTER publish barrier; they drain at the
// next top barrier with a full tile of compute in between (R4-verified overlap).
__global__ __launch_bounds__(256)
void attn_fwd(const bf16_t* __restrict__ Q, const bf16_t* __restrict__ Kh,
              const bf16_t* __restrict__ Vt, bf16_t* __restrict__ O,
              const int* __restrict__ causal_p)
{
  __shared__ __align__(16) bf16_t Ks[64 * 136];   // [key][dh] padded
  __shared__ __align__(16) bf16_t Vs[128 * 72];   // [dh][key] padded
  __shared__ __align__(16) bf16_t Ps[4][16 * 72]; // per-wave P relayout
  const int tid  = threadIdx.x;
  const int wave = tid >> 6, lane = tid & 63;
  const int quad = lane >> 4, l16 = lane & 15;
  const int id = blockIdx.x;
  const int bh = id & 31;                 // XCD-pinned per head
  const int qb = 31 - (id >> 5);          // heavy tiles dispatched first
  const int causal = *causal_p;

  const bf16_t* Qb = Q  + ((size_t)bh * S_LEN + qb * 64) * DH;
  const bf16_t* Kb = Kh + (size_t)bh * S_LEN * DH;
  const bf16_t* Vb = Vt + (size_t)bh * DH * S_LEN;

  bf16x8 qf[4];
#pragma unroll
  for (int kk = 0; kk < 4; ++kk)
    qf[kk] = *(const bf16x8*)(&Qb[(wave * 16 + l16) * DH + kk * 32 + quad * 8]);

  f32x4 oacc[8] = {};
  float mrow[4] = {NEG_BIG, NEG_BIG, NEG_BIG, NEG_BIG};
  float lrow[4] = {0.f, 0.f, 0.f, 0.f};

  const int nkb = causal ? (qb + 1) : (S_LEN / 64);

  float4 ka[4], va[4];   // prefetch registers (32 VGPRs)
#define LOAD_TILE(kb_)                                                          \
  {                                                                             \
    _Pragma("unroll")                                                           \
    for (int i = 0; i < 4; ++i) {                                               \
      int c = tid + i * 256;                                                    \
      ka[i] = *(const float4*)(&Kb[(size_t)((kb_) * 64 + (c >> 4)) * DH + ((c & 15) << 3)]); \
      va[i] = *(const float4*)(&Vb[(size_t)(c >> 3) * S_LEN + (kb_) * 64 + ((c & 7) << 3)]); \
    }                                                                           \
  }

  LOAD_TILE(0)
  for (int kb = 0; kb < nkb; ++kb) {
    if (kb) __syncthreads();             // all waves done reading tile kb-1
#pragma unroll
    for (int i = 0; i < 4; ++i) {
      int c = tid + i * 256;
      *(float4*)(&Ks[(c >> 4) * 136 + ((c & 15) << 3)]) = ka[i];
      *(float4*)(&Vs[(c >> 3) * 72 + ((c & 7) << 3)])   = va[i];
    }
    __syncthreads();                     // publish tile kb (nothing in flight)
    if (kb + 1 < nkb) LOAD_TILE(kb + 1)  // in flight across the whole compute

    // ---- scores S = Q K^T : 16x64 per wave ----
    f32x4 sc[4] = {};
#pragma unroll
    for (int kk = 0; kk < 4; ++kk) {
      bf16x8 kf[4];
#pragma unroll
      for (int nf = 0; nf < 4; ++nf)
        kf[nf] = *(const bf16x8*)(&Ks[(nf * 16 + l16) * 136 + kk * 32 + quad * 8]);
#pragma unroll
      for (int nf = 0; nf < 4; ++nf)
        sc[nf] = __builtin_amdgcn_mfma_f32_16x16x32_bf16(qf[kk], kf[nf], sc[nf], 0, 0, 0);
    }

    // ---- mask (diagonal tile only) + online softmax ----
    const bool do_mask = causal && (kb == qb);
    float p[4][4];  // [nf][r]
#pragma unroll
    for (int nf = 0; nf < 4; ++nf)
#pragma unroll
      for (int r = 0; r < 4; ++r) {
        float s = sc[nf][r];   // 1/sqrt(DH) pre-folded into Q
        if (do_mask && (nf * 16 + l16 > wave * 16 + quad * 4 + r)) s = NEG_BIG;
        p[nf][r] = s;
      }
#pragma unroll
    for (int r = 0; r < 4; ++r) {
      float mx = fmaxf(fmaxf(p[0][r], p[1][r]), fmaxf(p[2][r], p[3][r]));
#pragma unroll
      for (int d = 8; d >= 1; d >>= 1) mx = fmaxf(mx, __shfl_xor(mx, d));
      float mnew  = fmaxf(mrow[r], mx);
      float alpha = __expf(mrow[r] - mnew);
      mrow[r] = mnew;
      float rsum = 0.f;
#pragma unroll
      for (int nf = 0; nf < 4; ++nf) {
        float e = __expf(p[nf][r] - mnew);
        p[nf][r] = e;
        rsum += e;
      }
#pragma unroll
      for (int d = 8; d >= 1; d >>= 1) rsum += __shfl_xor(rsum, d);
      lrow[r] = lrow[r] * alpha + rsum;
#pragma unroll
      for (int nf = 0; nf < 8; ++nf) oacc[nf][r] *= alpha;
    }

    // ---- P: C-layout -> A-layout, wave-local (lgkmcnt only, no barrier) ----
    bf16_t* Pw = &Ps[wave][0];
#pragma unroll
    for (int r = 0; r < 4; ++r)
#pragma unroll
      for (int nf = 0; nf < 4; ++nf)
        Pw[(quad * 4 + r) * 72 + nf * 16 + l16] = (bf16_t)p[nf][r];
    asm volatile("s_waitcnt lgkmcnt(0)" ::: "memory");

    // ---- O += P V ----
#pragma unroll
    for (int ks = 0; ks < 2; ++ks) {
      bf16x8 pf = *(const bf16x8*)(&Pw[l16 * 72 + ks * 32 + quad * 8]);
#pragma unroll
      for (int nf = 0; nf < 8; ++nf) {
        bf16x8 vf = *(const bf16x8*)(&Vs[(nf * 16 + l16) * 72 + ks * 32 + quad * 8]);
        oacc[nf] = __builtin_amdgcn_mfma_f32_16x16x32_bf16(pf, vf, oacc[nf], 0, 0, 0);
      }
    }
    asm volatile("s_waitcnt lgkmcnt(0)" ::: "memory");  // Pw reads done before next write
  }

  // epilogue
  const int b = bh >> 4, h = bh & 15;
#pragma unroll
  for (int nf = 0; nf < 8; ++nf) {
    int dh = nf * 16 + l16;
#pragma unroll
    for (int r = 0; r < 4; ++r) {
      int s = qb * 64 + wave * 16 + quad * 4 + r;
      float vv = oacc[nf][r] / fmaxf(lrow[r], 1e-20f);
      O[((size_t)(b * S_LEN + s)) * DMODEL + h * DH + dh] = (bf16_t)vv;
    }
  }
}

extern "C" void kernel_launch(void* const* d_in, const int* in_sizes, int n_in,
                              void* d_out, int out_size, void* d_ws, size_t ws_size,
                              hipStream_t stream) {
  const float* q  = (const float*)d_in[0];
  const float* k  = (const float*)d_in[1];
  const float* v  = (const float*)d_in[2];
  const float* Wq = (const float*)d_in[3];
  const float* bq = (const float*)d_in[4];
  const float* Wk = (const float*)d_in[5];
  const float* bk = (const float*)d_in[6];
  const float* Wv = (const float*)d_in[7];
  const float* bv = (const float*)d_in[8];
  const float* Wo = (const float*)d_in[9];
  const float* bo = (const float*)d_in[10];
  const int*   cm = (const int*)d_in[11];

  float* out = (float*)d_out;
  const size_t NA = (size_t)MROWS * DMODEL;     // 8,388,608
  const size_t NW = (size_t)DMODEL * DMODEL;    // 4,194,304
  const float qscale = 0.08838834764831845f;    // 1/sqrt(128)

  bf16_t* p0 = (bf16_t*)d_ws;
  const size_t needA = (4 * NW + 7 * NA) * sizeof(bf16_t);  // ~151 MB
  const size_t needB = (4 * NW + 4 * NA) * sizeof(bf16_t);  // ~101 MB

  dim3 gg(MROWS / 128, DMODEL / 128), bb(256);
  dim3 cgW(2048), cgA(4096);
  bf16_t *Qh, *Kh, *Vh, *Ao;

  if (ws_size >= needA) {
    bf16_t *Wqb = p0, *Wkb = p0 + NW, *Wvb = p0 + 2 * NW, *Wob = p0 + 3 * NW;
    bf16_t *qb2 = p0 + 4 * NW, *kb2 = qb2 + NA, *vb2 = kb2 + NA;
    Qh = vb2 + NA; Kh = Qh + NA; Vh = Kh + NA; Ao = Vh + NA;
    cvt_bf16<<<cgW, bb, 0, stream>>>(Wq, Wqb, (int)(NW / 8));
    cvt_bf16<<<cgW, bb, 0, stream>>>(Wk, Wkb, (int)(NW / 8));
    cvt_bf16<<<cgW, bb, 0, stream>>>(Wv, Wvb, (int)(NW / 8));
    cvt_bf16<<<cgW, bb, 0, stream>>>(Wo, Wob, (int)(NW / 8));
    cvt_bf16<<<cgA, bb, 0, stream>>>(q, qb2, (int)(NA / 8));
    cvt_bf16<<<cgA, bb, 0, stream>>>(k, kb2, (int)(NA / 8));
    cvt_bf16<<<cgA, bb, 0, stream>>>(v, vb2, (int)(NA / 8));
    gemm_bt<bf16_t, bf16_t, bf16_t><<<gg, bb, 0, stream>>>(qb2, Wqb, bq, Qh, 1, qscale);
    gemm_bt<bf16_t, bf16_t, bf16_t><<<gg, bb, 0, stream>>>(kb2, Wkb, bk, Kh, 1, 1.0f);
    gemm_bt<bf16_t, bf16_t, bf16_t><<<gg, bb, 0, stream>>>(vb2, Wvb, bv, Vh, 2, 1.0f);
    attn_fwd<<<dim3(1024), bb, 0, stream>>>(Qh, Kh, Vh, Ao, cm);
    gemm_bt<bf16_t, bf16_t, float><<<gg, bb, 0, stream>>>(Ao, Wob, bo, out, 0, 1.0f);
  } else if (ws_size >= needB) {
    bf16_t *Wqb = p0, *Wkb = p0 + NW, *Wvb = p0 + 2 * NW, *Wob = p0 + 3 * NW;
    Qh = p0 + 4 * NW; Kh = Qh + NA; Vh = Kh + NA; Ao = Vh + NA;
    cvt_bf16<<<cgW, bb, 0, stream>>>(Wq, Wqb, (int)(NW / 8));
    cvt_bf16<<<cgW, bb, 0, stream>>>(Wk, Wkb, (int)(NW / 8));
    cvt_bf16<<<cgW, bb, 0, stream>>>(Wv, Wvb, (int)(NW / 8));
    cvt_bf16<<<cgW, bb, 0, stream>>>(Wo, Wob, (int)(NW / 8));
    gemm_bt<float, bf16_t, bf16_t><<<gg, bb, 0, stream>>>(q, Wqb, bq, Qh, 1, qscale);
    gemm_bt<float, bf16_t, bf16_t><<<gg, bb, 0, stream>>>(k, Wkb, bk, Kh, 1, 1.0f);
    gemm_bt<float, bf16_t, bf16_t><<<gg, bb, 0, stream>>>(v, Wvb, bv, Vh, 2, 1.0f);
    attn_fwd<<<dim3(1024), bb, 0, stream>>>(Qh, Kh, Vh, Ao, cm);
    gemm_bt<bf16_t, bf16_t, float><<<gg, bb, 0, stream>>>(Ao, Wob, bo, out, 0, 1.0f);
  } else {
    Qh = p0; Kh = Qh + NA; Vh = Kh + NA; Ao = Vh + NA;
    gemm_bt<float, float, bf16_t><<<gg, bb, 0, stream>>>(q, Wq, bq, Qh, 1, qscale);
    gemm_bt<float, float, bf16_t><<<gg, bb, 0, stream>>>(k, Wk, bk, Kh, 1, 1.0f);
    gemm_bt<float, float, bf16_t><<<gg, bb, 0, stream>>>(v, Wv, bv, Vh, 2, 1.0f);
    attn_fwd<<<dim3(1024), bb, 0, stream>>>(Qh, Kh, Vh, Ao, cm);
    gemm_bt<bf16_t, float, float><<<gg, bb, 0, stream>>>(Ao, Wo, bo, out, 0, 1.0f);
  }
}